// Round 14
// baseline (212.039 us; speedup 1.0000x reference)
//
#include <hip/hip_runtime.h>
#include <hip/hip_bf16.h>
#include <math.h>

#define B_ 8
#define S_ 128
#define H_ 768
#define NH_ 12
#define HD_ 64
#define M_ 1024
#define KW_ 100
#define I_ 3072
#define QKVN 2304
#define NCHUNK 5
#define KWPER 20
#define LOG2E 1.4426950408889634f

typedef __attribute__((ext_vector_type(8))) short short8;
typedef __attribute__((ext_vector_type(8))) unsigned short ushort8;
typedef __attribute__((ext_vector_type(4))) float f32x4;
typedef __attribute__((ext_vector_type(4))) short s4b;   // 4x bf16 (2 VGPR) for 16x16x16 mfma

static __device__ __forceinline__ unsigned short f2b(float f) {
  union { float f; unsigned int u; } v; v.f = f;
  return (unsigned short)((v.u + 0x7fffu + ((v.u >> 16) & 1u)) >> 16);
}
static __device__ __forceinline__ float b2f(unsigned short b) {
  union { unsigned int u; float f; } v; v.u = ((unsigned int)b) << 16;
  return v.f;
}
// async global->LDS 16B (dest must be base+lane*16 linear within the wave)
static __device__ __forceinline__ void gload16(const unsigned short* g, unsigned short* l) {
  __builtin_amdgcn_global_load_lds((const __attribute__((address_space(1))) unsigned int*)g,
                                   (__attribute__((address_space(3))) unsigned int*)l, 16, 0, 0);
}

// ---------------- merged prep kernel ----------------
__global__ void k_prep(const float* __restrict__ hidden,
                       const float* __restrict__ Wq, const float* __restrict__ Wk,
                       const float* __restrict__ Wv, const float* __restrict__ Wo,
                       const float* __restrict__ Wdown, const float* __restrict__ Wup,
                       const float* __restrict__ posk, const float* __restrict__ negk,
                       const float* __restrict__ Wmlp, const float* __restrict__ bmlp,
                       const float* __restrict__ bo,
                       unsigned short* __restrict__ hb, unsigned short* __restrict__ qkvT,
                       unsigned short* __restrict__ WoT, unsigned short* __restrict__ WdownT,
                       unsigned short* __restrict__ WupT,
                       float* __restrict__ kw2s, float* __restrict__ kwm, float* __restrict__ c0) {
  __shared__ float tile[32][33];
  int z = blockIdx.z;
  int t = threadIdx.x;
  if (z == 6) {
    int n = blockIdx.y * 96 + blockIdx.x;
    if (n < 768) {
      int i = (n * 256 + t) * 4;
      float4 v = *(const float4*)&hidden[i];
      uint2 o;
      o.x = (unsigned)f2b(v.x) | ((unsigned)f2b(v.y) << 16);
      o.y = (unsigned)f2b(v.z) | ((unsigned)f2b(v.w) << 16);
      *(uint2*)&hb[i] = o;
    } else if (n < 1068) {
      int idx = (n - 768) * 256 + t;
      if (idx < KW_ * H_) {
        int j = idx / H_, d = idx - j * H_;
        float v = (j & 1) ? negk[(j >> 1) * H_ + d] : posk[(j >> 1) * H_ + d];
        kw2s[idx] = v * v * 0.125f * LOG2E;
        kwm[idx] = v * Wmlp[j];
      }
    } else if (n == 1068) {
      __shared__ float red[256];
      red[t] = (t < KW_) ? Wmlp[t] : 0.f;
      __syncthreads();
      for (int s = 128; s > 0; s >>= 1) { if (t < s) red[t] += red[t + s]; __syncthreads(); }
      float sWm = red[0];
      for (int c = t; c < H_; c += 256) c0[c] = sWm * bo[c] + bmlp[0];
    }
    return;
  }
  const float* src; unsigned short* dst; int R, C, r0, c0t;
  if (z < 4) {
    if (blockIdx.x >= 24) return;
    const float* srcs[4] = {Wq, Wk, Wv, Wo};
    src = srcs[z];
    dst = (z < 3) ? qkvT + (size_t)z * 768 * 768 : WoT;
    R = 768; C = 768; c0t = blockIdx.x * 32; r0 = blockIdx.y * 32;
  } else if (z == 4) {
    src = Wdown; dst = WdownT; R = 768; C = 3072;
    c0t = blockIdx.x * 32; r0 = blockIdx.y * 32;
  } else {
    src = Wup; dst = WupT; R = 3072; C = 768;
    c0t = blockIdx.y * 32; r0 = blockIdx.x * 32;
  }
  int tx = t & 31, ty = t >> 5;
#pragma unroll
  for (int i = 0; i < 4; i++)
    tile[ty + i * 8][tx] = src[(size_t)(r0 + ty + i * 8) * C + c0t + tx];
  __syncthreads();
#pragma unroll
  for (int i = 0; i < 4; i++)
    dst[(size_t)(c0t + ty + i * 8) * R + r0 + tx] = f2b(tile[tx][ty + i * 8]);
}

// ---------------- bf16 MFMA GEMM (global_load_lds staging; EPI0=bf16 out, EPI2=gelu) ----------------
template <int EPI>
__launch_bounds__(256)
__global__ void k_gemm_bt(const unsigned short* __restrict__ A, const unsigned short* __restrict__ BT,
                          int M, int N, int K,
                          float* __restrict__ outF, unsigned short* __restrict__ outB,
                          const float* __restrict__ bias, const float* __restrict__ res) {
  __shared__ __align__(16) unsigned short Asm[128 * 32];
  __shared__ __align__(16) unsigned short Bsm[128 * 32];
  int tid = threadIdx.x;
  int lane = tid & 63, wid = tid >> 6;
  int g = lane >> 4, c16 = lane & 15;
  int wr = wid >> 1, wc = wid & 1;
  int m0 = blockIdx.y * 128, n0 = blockIdx.x * 128;
  f32x4 acc[4][4] = {};
  int ldsrow = lane >> 2, ldscol = (lane & 3) * 8;
  for (int kt = 0; kt < K; kt += 32) {
    __syncthreads();
#pragma unroll
    for (int r = 0; r < 2; r++) {
      int c = wid * 2 + r;
      gload16(A + (size_t)(m0 + c * 16 + ldsrow) * K + kt + ldscol, &Asm[c * 512 + lane * 8]);
      gload16(BT + (size_t)(n0 + c * 16 + ldsrow) * K + kt + ldscol, &Bsm[c * 512 + lane * 8]);
    }
    __syncthreads();
    short8 af[4], bf[4];
#pragma unroll
    for (int mi = 0; mi < 4; mi++) af[mi] = *(const short8*)&Asm[(wr * 64 + mi * 16 + c16) * 32 + g * 8];
#pragma unroll
    for (int ni = 0; ni < 4; ni++) bf[ni] = *(const short8*)&Bsm[(wc * 64 + ni * 16 + c16) * 32 + g * 8];
#pragma unroll
    for (int mi = 0; mi < 4; mi++)
#pragma unroll
      for (int ni = 0; ni < 4; ni++)
        acc[mi][ni] = __builtin_amdgcn_mfma_f32_16x16x32_bf16(af[mi], bf[ni], acc[mi][ni], 0, 0, 0);
  }
#pragma unroll
  for (int mi = 0; mi < 4; mi++)
#pragma unroll
    for (int ni = 0; ni < 4; ni++)
#pragma unroll
      for (int rr = 0; rr < 4; rr++) {
        int row = m0 + wr * 64 + mi * 16 + g * 4 + rr;
        int col = n0 + wc * 64 + ni * 16 + c16;
        float v = acc[mi][ni][rr];
        if (EPI == 0) {
          outB[(size_t)row * N + col] = f2b(v);
        } else if (EPI == 2) {
          float t = v + bias[col];
          float gl = 0.5f * t * (1.f + erff(t * 0.70710678118f));
          outB[(size_t)row * N + col] = f2b(gl);
        }
      }
}

// ---------------- split-K GEMM -> partials (OUTB=1: bf16, else f32) ----------------
template <int OUTB>
__launch_bounds__(256)
__global__ void k_gemm_sk(const unsigned short* __restrict__ A, const unsigned short* __restrict__ BT,
                          int M, int N, int K, int ksl, void* __restrict__ pOut) {
  __shared__ __align__(16) unsigned short Asm[128 * 32];
  __shared__ __align__(16) unsigned short Bsm[128 * 32];
  int tid = threadIdx.x;
  int lane = tid & 63, wid = tid >> 6;
  int g = lane >> 4, c16 = lane & 15;
  int wr = wid >> 1, wc = wid & 1;
  int m0 = blockIdx.y * 128, n0 = blockIdx.x * 128;
  int kstart = blockIdx.z * ksl;
  f32x4 acc[4][4] = {};
  int ldsrow = lane >> 2, ldscol = (lane & 3) * 8;
  for (int kt = 0; kt < ksl; kt += 32) {
    __syncthreads();
#pragma unroll
    for (int r = 0; r < 2; r++) {
      int c = wid * 2 + r;
      gload16(A + (size_t)(m0 + c * 16 + ldsrow) * K + kstart + kt + ldscol, &Asm[c * 512 + lane * 8]);
      gload16(BT + (size_t)(n0 + c * 16 + ldsrow) * K + kstart + kt + ldscol, &Bsm[c * 512 + lane * 8]);
    }
    __syncthreads();
    short8 af[4], bf[4];
#pragma unroll
    for (int mi = 0; mi < 4; mi++) af[mi] = *(const short8*)&Asm[(wr * 64 + mi * 16 + c16) * 32 + g * 8];
#pragma unroll
    for (int ni = 0; ni < 4; ni++) bf[ni] = *(const short8*)&Bsm[(wc * 64 + ni * 16 + c16) * 32 + g * 8];
#pragma unroll
    for (int mi = 0; mi < 4; mi++)
#pragma unroll
      for (int ni = 0; ni < 4; ni++)
        acc[mi][ni] = __builtin_amdgcn_mfma_f32_16x16x32_bf16(af[mi], bf[ni], acc[mi][ni], 0, 0, 0);
  }
#pragma unroll
  for (int mi = 0; mi < 4; mi++)
#pragma unroll
    for (int ni = 0; ni < 4; ni++)
#pragma unroll
      for (int rr = 0; rr < 4; rr++) {
        int row = m0 + wr * 64 + mi * 16 + g * 4 + rr;
        int col = n0 + wc * 64 + ni * 16 + c16;
        if (OUTB) {
          unsigned short* dst = (unsigned short*)pOut + (size_t)blockIdx.z * M * N;
          dst[(size_t)row * N + col] = f2b(acc[mi][ni][rr]);
        } else {
          float* dst = (float*)pOut + (size_t)blockIdx.z * M * N;
          dst[(size_t)row * N + col] = acc[mi][ni][rr];
        }
      }
}

// reduce SPLITS f32 partials (+ optional bias epilogue)
template <int SPLITS, int EPI>
__global__ void k_red(const float* __restrict__ p, const float* __restrict__ bias,
                      float* __restrict__ outF, unsigned short* __restrict__ outB, int N) {
  int i = (blockIdx.x * 256 + threadIdx.x) * 4;
  const size_t MN = (size_t)M_ * N;
  float4 s = *(const float4*)&p[i];
#pragma unroll
  for (int c = 1; c < SPLITS; c++) {
    float4 v = *(const float4*)&p[c * MN + i];
    s.x += v.x; s.y += v.y; s.z += v.z; s.w += v.w;
  }
  if (EPI == 1) {
    int col = i % N;
    s.x += bias[col]; s.y += bias[col + 1]; s.z += bias[col + 2]; s.w += bias[col + 3];
    *(float4*)&outF[i] = s;
  }
  uint2 o;
  o.x = (unsigned)f2b(s.x) | ((unsigned)f2b(s.y) << 16);
  o.y = (unsigned)f2b(s.z) | ((unsigned)f2b(s.w) << 16);
  *(uint2*)&outB[i] = o;
}

// reduce SPLITS bf16 partials -> bf16
template <int SPLITS>
__global__ void k_redb(const unsigned short* __restrict__ p, unsigned short* __restrict__ outB,
                       size_t MN) {
  int i = (blockIdx.x * 256 + threadIdx.x) * 4;
  float s0 = 0.f, s1 = 0.f, s2 = 0.f, s3 = 0.f;
#pragma unroll
  for (int c = 0; c < SPLITS; c++) {
    uint2 v = *(const uint2*)&p[c * MN + i];
    s0 += b2f((unsigned short)(v.x & 0xffffu));
    s1 += b2f((unsigned short)(v.x >> 16));
    s2 += b2f((unsigned short)(v.y & 0xffffu));
    s3 += b2f((unsigned short)(v.y >> 16));
  }
  uint2 o;
  o.x = (unsigned)f2b(s0) | ((unsigned)f2b(s1) << 16);
  o.y = (unsigned)f2b(s2) | ((unsigned)f2b(s3) << 16);
  *(uint2*)&outB[i] = o;
}

// ---------------- fused keyword attention (v13: q-halved waves, reg-resident Q) ----------------
// 1D grid 480 (XCD-clustered). 512 thr = 8 waves: strip = wid>>1 owns keys
// [strip*32,+32), qh = wid&1 owns q [qh*64,+64). Q-half, K-rows, V-frags all
// VGPR-resident -> ZERO in-loop Q ds_reads (was the dominant pipe: 8x LDS
// re-read amplification). Cross-qhalf colsum via tiny double-buffered X in LDS
// (ONE barrier/kw; double-buffer makes WAR safe by barrier induction).
__launch_bounds__(512, 2)
__global__ void k_attn(const unsigned short* __restrict__ PQKV,
                       const float* __restrict__ kw2s, const float* __restrict__ kwm,
                       unsigned short* __restrict__ partial) {
  __shared__ __align__(16) char SM[33792];  // VS [128][72] bf16 (prologue) / Ebuf [8][16][66] f32 (epilogue)
  __shared__ float X[2][8][32];             // 2KB colsum exchange (double-buffered)
  int tid = threadIdx.x;
  int lane = tid & 63, wid = tid >> 6;
  int g = (lane >> 4) & 3, c16 = lane & 15;
  int n = blockIdx.x;
  int chunk = (n >> 3) % NCHUNK;
  int hb = (n & 7) + 8 * (n / (8 * NCHUNK));
  int h = hb >> 3, b = hb & 7;
  int strip = wid >> 1, qh = wid & 1;
  int kb = strip * 32, qbase = qh * 64;
  const size_t rowbase = (size_t)b * 128 * QKVN;
  const unsigned short* Qbase = PQKV + rowbase + h * HD_;
  const unsigned short* Kbase = Qbase + H_;
  const unsigned short* Vbase = Qbase + 2 * H_;

  unsigned short (*VS)[72] = (unsigned short(*)[72])SM;
  // ---- prologue: stage V rows -> VS; Q-half and K-rows -> registers ----
  {
    int kq = tid >> 2, quarter = tid & 3;
    const unsigned short* srcv = Vbase + (size_t)kq * QKVN + quarter * 16;
    ushort8 w0 = *(const ushort8*)srcv;
    ushort8 w1 = *(const ushort8*)(srcv + 8);
    *(ushort8*)&VS[kq][quarter * 16] = w0;
    *(ushort8*)&VS[kq][quarter * 16 + 8] = w1;
  }
  ushort8 qf[4][2];
#pragma unroll
  for (int t = 0; t < 4; t++) {
    const unsigned short* qr = Qbase + (size_t)(qbase + 16 * t + c16) * QKVN;
    qf[t][0] = *(const ushort8*)(qr + g * 8);
    qf[t][1] = *(const ushort8*)(qr + 32 + g * 8);
  }
  ushort8 kraw[2][2];
#pragma unroll
  for (int sub = 0; sub < 2; sub++) {
    const unsigned short* kr = Kbase + (size_t)(kb + sub * 16 + c16) * QKVN;
    kraw[sub][0] = *(const ushort8*)(kr + g * 8);
    kraw[sub][1] = *(const ushort8*)(kr + 32 + g * 8);
  }
  __syncthreads();
  // V frags: vraw[dt][sub][j] = V[kb+sub*16+4g+j][dt*16+c16]
  unsigned short vraw[4][2][4];
#pragma unroll
  for (int dt = 0; dt < 4; dt++)
#pragma unroll
    for (int sub = 0; sub < 2; sub++)
#pragma unroll
      for (int j = 0; j < 4; j++)
        vraw[dt][sub][j] = VS[kb + sub * 16 + 4 * g + j][dt * 16 + c16];

  f32x4 acc[4][4] = {};  // [dt][t] : ctx^T[d=dt*16+4g+rr][q=qbase+16t+c16], partial over strip
  for (int ki = 0; ki < KWPER; ki++) {
    int kwi = chunk * KWPER + ki;
    const float* k2p = kw2s + (size_t)kwi * H_ + h * HD_;
    const float* kmp = kwm + (size_t)kwi * H_ + h * HD_;
    // ---- K' = K * kw2 for both sub-strips ----
    short8 kA[2][2];
    {
      float4 s0 = *(const float4*)(k2p + g * 8);
      float4 s1 = *(const float4*)(k2p + g * 8 + 4);
      float4 s2 = *(const float4*)(k2p + 32 + g * 8);
      float4 s3 = *(const float4*)(k2p + 32 + g * 8 + 4);
#pragma unroll
      for (int sub = 0; sub < 2; sub++) {
        union { unsigned u[4]; short8 v; } p0, p1;
        asm("v_cvt_pk_bf16_f32 %0, %1, %2" : "=v"(p0.u[0]) : "v"(b2f(kraw[sub][0][0]) * s0.x), "v"(b2f(kraw[sub][0][1]) * s0.y));
        asm("v_cvt_pk_bf16_f32 %0, %1, %2" : "=v"(p0.u[1]) : "v"(b2f(kraw[sub][0][2]) * s0.z), "v"(b2f(kraw[sub][0][3]) * s0.w));
        asm("v_cvt_pk_bf16_f32 %0, %1, %2" : "=v"(p0.u[2]) : "v"(b2f(kraw[sub][0][4]) * s1.x), "v"(b2f(kraw[sub][0][5]) * s1.y));
        asm("v_cvt_pk_bf16_f32 %0, %1, %2" : "=v"(p0.u[3]) : "v"(b2f(kraw[sub][0][6]) * s1.z), "v"(b2f(kraw[sub][0][7]) * s1.w));
        asm("v_cvt_pk_bf16_f32 %0, %1, %2" : "=v"(p1.u[0]) : "v"(b2f(kraw[sub][1][0]) * s2.x), "v"(b2f(kraw[sub][1][1]) * s2.y));
        asm("v_cvt_pk_bf16_f32 %0, %1, %2" : "=v"(p1.u[1]) : "v"(b2f(kraw[sub][1][2]) * s2.z), "v"(b2f(kraw[sub][1][3]) * s2.w));
        asm("v_cvt_pk_bf16_f32 %0, %1, %2" : "=v"(p1.u[2]) : "v"(b2f(kraw[sub][1][4]) * s3.x), "v"(b2f(kraw[sub][1][5]) * s3.y));
        asm("v_cvt_pk_bf16_f32 %0, %1, %2" : "=v"(p1.u[3]) : "v"(b2f(kraw[sub][1][6]) * s3.z), "v"(b2f(kraw[sub][1][7]) * s3.w));
        kA[sub][0] = p0.v; kA[sub][1] = p1.v;
      }
    }
    // ---- QK^T swapped (all from regs) + exp2 + inline colsum + pack ----
    float csum[2][4] = {};
    s4b pw[2][4];
    __builtin_amdgcn_s_setprio(1);
#pragma unroll
    for (int t = 0; t < 4; t++)
#pragma unroll
      for (int sub = 0; sub < 2; sub++) {
        f32x4 z = {0.f, 0.f, 0.f, 0.f};
        z = __builtin_amdgcn_mfma_f32_16x16x32_bf16(kA[sub][0], *(const short8*)&qf[t][0], z, 0, 0, 0);
        z = __builtin_amdgcn_mfma_f32_16x16x32_bf16(kA[sub][1], *(const short8*)&qf[t][1], z, 0, 0, 0);
        float e0 = __builtin_amdgcn_exp2f(z[0]);
        float e1 = __builtin_amdgcn_exp2f(z[1]);
        float e2 = __builtin_amdgcn_exp2f(z[2]);
        float e3 = __builtin_amdgcn_exp2f(z[3]);
        csum[sub][0] += e0; csum[sub][1] += e1; csum[sub][2] += e2; csum[sub][3] += e3;
        union { unsigned u[2]; s4b v; } pp;
        asm("v_cvt_pk_bf16_f32 %0, %1, %2" : "=v"(pp.u[0]) : "v"(e0), "v"(e1));
        asm("v_cvt_pk_bf16_f32 %0, %1, %2" : "=v"(pp.u[1]) : "v"(e2), "v"(e3));
        pw[sub][t] = pp.v;
      }
    __builtin_amdgcn_s_setprio(0);
    // ---- butterfly over own q-half (c16 lanes) ----
#pragma unroll
    for (int sub = 0; sub < 2; sub++)
#pragma unroll
      for (int rr = 0; rr < 4; rr++) {
        float s = csum[sub][rr];
        s += __shfl_xor(s, 1);
        s += __shfl_xor(s, 2);
        s += __shfl_xor(s, 4);
        s += __shfl_xor(s, 8);
        csum[sub][rr] = s;
      }
    // ---- cross-qhalf exchange via double-buffered X (one barrier) ----
    int buf = ki & 1;
    if (!(lane & 15)) {
#pragma unroll
      for (int sub = 0; sub < 2; sub++)
#pragma unroll
        for (int rr = 0; rr < 4; rr++)
          X[buf][wid][sub * 16 + 4 * g + rr] = csum[sub][rr];
    }
    __syncthreads();
    float cs[2][4];
#pragma unroll
    for (int sub = 0; sub < 2; sub++)
#pragma unroll
      for (int rr = 0; rr < 4; rr++)
        cs[sub][rr] = __builtin_amdgcn_rcpf(csum[sub][rr] + X[buf][wid ^ 1][sub * 16 + 4 * g + rr]);
    // ---- V'' = V * kwm[d] * cs[k] ----
    s4b vA[4][2];
#pragma unroll
    for (int dt = 0; dt < 4; dt++) {
      float km = kmp[dt * 16 + c16];
#pragma unroll
      for (int sub = 0; sub < 2; sub++) {
        union { unsigned u[2]; s4b v; } pv;
        asm("v_cvt_pk_bf16_f32 %0, %1, %2" : "=v"(pv.u[0])
            : "v"(b2f(vraw[dt][sub][0]) * km * cs[sub][0]), "v"(b2f(vraw[dt][sub][1]) * km * cs[sub][1]));
        asm("v_cvt_pk_bf16_f32 %0, %1, %2" : "=v"(pv.u[1])
            : "v"(b2f(vraw[dt][sub][2]) * km * cs[sub][2]), "v"(b2f(vraw[dt][sub][3]) * km * cs[sub][3]));
        vA[dt][sub] = pv.v;
      }
    }
    // ---- PV swapped over 2 sub-strips ----
    __builtin_amdgcn_s_setprio(1);
#pragma unroll
    for (int dt = 0; dt < 4; dt++)
#pragma unroll
      for (int t = 0; t < 4; t++) {
        acc[dt][t] = __builtin_amdgcn_mfma_f32_16x16x16bf16_1k(vA[dt][0], pw[0][t], acc[dt][t], 0, 0, 0);
        acc[dt][t] = __builtin_amdgcn_mfma_f32_16x16x16bf16_1k(vA[dt][1], pw[1][t], acc[dt][t], 0, 0, 0);
      }
    __builtin_amdgcn_s_setprio(0);
  }
  // ---- epilogue: reduce 4 strips per q-half via LDS, 4 rounds over dt ----
  float (*Ebuf)[16][66] = (float(*)[16][66])SM;
  int qo2 = tid & 63;
  int rest = tid >> 6;       // 0..7
  int qhx = rest & 1;
  int dd = rest >> 1;        // 0..3
#pragma unroll
  for (int dt = 0; dt < 4; dt++) {
    __syncthreads();
#pragma unroll
    for (int t = 0; t < 4; t++)
#pragma unroll
      for (int rr = 0; rr < 4; rr++)
        Ebuf[wid][4 * g + rr][16 * t + c16] = acc[dt][t][rr];
    __syncthreads();
    float sj[4];
#pragma unroll
    for (int j = 0; j < 4; j++) {
      float v = 0.f;
#pragma unroll
      for (int s4 = 0; s4 < 4; s4++) v += Ebuf[2 * s4 + qhx][dd * 4 + j][qo2];
      sj[j] = v;
    }
    int row = b * 128 + qhx * 64 + qo2;
    int col = h * HD_ + dt * 16 + dd * 4;
    unsigned short* o = partial + (size_t)chunk * M_ * H_ + (size_t)row * H_ + col;
    uint2 ov;
    ov.x = (unsigned)f2b(sj[0]) | ((unsigned)f2b(sj[1]) << 16);
    ov.y = (unsigned)f2b(sj[2]) | ((unsigned)f2b(sj[3]) << 16);
    *(uint2*)o = ov;
  }
}

// LayerNorm with fused up-proj split-K (bf16 partials) reduce + bias + residual
__launch_bounds__(256)
__global__ void k_ln2(const unsigned short* __restrict__ pUp, const float* __restrict__ bup,
                      const float* __restrict__ fusedF,
                      const float* __restrict__ gamma, const float* __restrict__ beta,
                      float* __restrict__ out) {
  __shared__ float red[8];
  int row = blockIdx.x, t = threadIdx.x;
  int lane = t & 63, wid = t >> 6;
  const size_t MN = (size_t)M_ * H_;
  const size_t rb = (size_t)row * H_;
  float v[3];
#pragma unroll
  for (int j = 0; j < 3; j++) {
    int c = t + j * 256;
    float x = b2f(pUp[rb + c]) + b2f(pUp[MN + rb + c]) + b2f(pUp[2 * MN + rb + c]) + b2f(pUp[3 * MN + rb + c]);
    v[j] = x + bup[c] + fusedF[rb + c];
  }
  float s = v[0] + v[1] + v[2];
#pragma unroll
  for (int off = 1; off < 64; off <<= 1) s += __shfl_xor(s, off);
  if (lane == 0) red[wid] = s;
  __syncthreads();
  float mu = (red[0] + red[1] + red[2] + red[3]) * (1.f / 768.f);
  float q = 0.f;
#pragma unroll
  for (int j = 0; j < 3; j++) { float d = v[j] - mu; q += d * d; }
#pragma unroll
  for (int off = 1; off < 64; off <<= 1) q += __shfl_xor(q, off);
  if (lane == 0) red[4 + wid] = q;
  __syncthreads();
  float var = (red[4] + red[5] + red[6] + red[7]) * (1.f / 768.f);
  float rstd = rsqrtf(var + 1e-12f);
#pragma unroll
  for (int j = 0; j < 3; j++) {
    int c = t + j * 256;
    out[rb + c] = gamma[c] * ((v[j] - mu) * rstd) + beta[c];
  }
}

// ---------------- launch ----------------

extern "C" void kernel_launch(void* const* d_in, const int* in_sizes, int n_in,
                              void* d_out, int out_size, void* d_ws, size_t ws_size,
                              hipStream_t stream) {
  const float* hidden = (const float*)d_in[0];
  const float* posk   = (const float*)d_in[1];
  const float* negk   = (const float*)d_in[2];
  const float* Wq     = (const float*)d_in[4];
  const float* Wk     = (const float*)d_in[5];
  const float* Wv     = (const float*)d_in[6];
  const float* Wo     = (const float*)d_in[7];
  const float* bo     = (const float*)d_in[8];
  const float* Wmlp   = (const float*)d_in[9];
  const float* bmlp   = (const float*)d_in[10];
  const float* Wdown  = (const float*)d_in[11];
  const float* bdown  = (const float*)d_in[12];
  const float* Wup    = (const float*)d_in[13];
  const float* bup    = (const float*)d_in[14];
  const float* gamma  = (const float*)d_in[15];
  const float* beta   = (const float*)d_in[16];

  char* ws = (char*)d_ws;
  size_t off = 0;
  auto alloc = [&](size_t bytes) -> void* {
    void* p = ws + off;
    off += (bytes + 255) & ~(size_t)255;
    return p;
  };
  unsigned short* hb     = (unsigned short*)alloc((size_t)M_ * H_ * 2);
  unsigned short* qkvT   = (unsigned short*)alloc((size_t)QKVN * H_ * 2);
  unsigned short* WoT    = (unsigned short*)alloc((size_t)H_ * H_ * 2);
  unsigned short* WdownT = (unsigned short*)alloc((size_t)I_ * H_ * 2);
  unsigned short* WupT   = (unsigned short*)alloc((size_t)H_ * I_ * 2);
  unsigned short* PQKV   = (unsigned short*)alloc((size_t)M_ * QKVN * 2);
  float* kw2s    = (float*)alloc((size_t)KW_ * H_ * 4);
  float* kwm     = (float*)alloc((size_t)KW_ * H_ * 4);
  float* c0      = (float*)alloc((size_t)H_ * 4);
  float* partial = (float*)alloc((size_t)10 * M_ * H_ * 4);  // aliased: attn bf16 x5 / Wo f32 sk / up bf16 sk
  unsigned short* ctxsum = (unsigned short*)alloc((size_t)M_ * H_ * 2);
  float* fusedF  = (float*)alloc((size_t)M_ * H_ * 4);
  unsigned short* fusedB = (unsigned short*)alloc((size_t)M_ * H_ * 2);
  unsigned short* downB  = (unsigned short*)alloc((size_t)M_ * I_ * 2);

  k_prep<<<dim3(96, 24, 7), 256, 0, stream>>>(hidden, Wq, Wk, Wv, Wo, Wdown, Wup,
                                              posk, negk, Wmlp, bmlp, bo,
                                              hb, qkvT, WoT, WdownT, WupT, kw2s, kwm, c0);
  // QKV projection: direct
  k_gemm_bt<0><<<dim3(18, 8), 256, 0, stream>>>(hb, qkvT, M_, QKVN, H_, nullptr, PQKV, nullptr, nullptr);
  k_attn<<<NCHUNK * NH_ * B_, 512, 0, stream>>>(PQKV, kw2s, kwm, (unsigned short*)partial);
  k_redb<NCHUNK><<<768, 256, 0, stream>>>((const unsigned short*)partial, ctxsum, (size_t)M_ * H_);
  // Wo: split-K x4 (f32 partials) ; reduce adds c0 (= sum(Wmlp)*bo + bmlp)
  k_gemm_sk<0><<<dim3(6, 8, 4), 256, 0, stream>>>(ctxsum, WoT, M_, H_, H_, 192, partial);
  k_red<4, 1><<<768, 256, 0, stream>>>(partial, c0, fusedF, fusedB, H_);
  // down-proj: fused gelu epilogue
  k_gemm_bt<2><<<dim3(24, 8), 256, 0, stream>>>(fusedB, WdownT, M_, I_, H_, nullptr, downB, bdown, nullptr);
  // up-proj: split-K x4 bf16 partials ; reduce + bias + residual + LN fused into k_ln2
  k_gemm_sk<1><<<dim3(6, 8, 4), 256, 0, stream>>>(downB, WupT, M_, H_, I_, 768, partial);
  k_ln2<<<M_, 256, 0, stream>>>((const unsigned short*)partial, bup, fusedF, gamma, beta, (float*)d_out);
}

// Round 15
// 175.071 us; speedup vs baseline: 1.2112x; 1.2112x over previous
//
#include <hip/hip_runtime.h>
#include <hip/hip_bf16.h>
#include <math.h>

#define B_ 8
#define S_ 128
#define H_ 768
#define NH_ 12
#define HD_ 64
#define M_ 1024
#define KW_ 100
#define I_ 3072
#define QKVN 2304
#define NCHUNK 5
#define KWPER 20
#define LOG2E 1.4426950408889634f

typedef __attribute__((ext_vector_type(8))) short short8;
typedef __attribute__((ext_vector_type(8))) unsigned short ushort8;
typedef __attribute__((ext_vector_type(4))) float f32x4;
typedef __attribute__((ext_vector_type(4))) short s4b;   // 4x bf16 (2 VGPR) for 16x16x16 mfma

static __device__ __forceinline__ unsigned short f2b(float f) {
  union { float f; unsigned int u; } v; v.f = f;
  return (unsigned short)((v.u + 0x7fffu + ((v.u >> 16) & 1u)) >> 16);
}
static __device__ __forceinline__ float b2f(unsigned short b) {
  union { unsigned int u; float f; } v; v.u = ((unsigned int)b) << 16;
  return v.f;
}
// async global->LDS 16B (dest must be base+lane*16 linear within the wave)
static __device__ __forceinline__ void gload16(const unsigned short* g, unsigned short* l) {
  __builtin_amdgcn_global_load_lds((const __attribute__((address_space(1))) unsigned int*)g,
                                   (__attribute__((address_space(3))) unsigned int*)l, 16, 0, 0);
}

// ---------------- merged prep kernel ----------------
__global__ void k_prep(const float* __restrict__ hidden,
                       const float* __restrict__ Wq, const float* __restrict__ Wk,
                       const float* __restrict__ Wv, const float* __restrict__ Wo,
                       const float* __restrict__ Wdown, const float* __restrict__ Wup,
                       const float* __restrict__ posk, const float* __restrict__ negk,
                       const float* __restrict__ Wmlp, const float* __restrict__ bmlp,
                       const float* __restrict__ bo,
                       unsigned short* __restrict__ hb, unsigned short* __restrict__ qkvT,
                       unsigned short* __restrict__ WoT, unsigned short* __restrict__ WdownT,
                       unsigned short* __restrict__ WupT,
                       float* __restrict__ kw2s, float* __restrict__ kwm, float* __restrict__ c0) {
  __shared__ float tile[32][33];
  int z = blockIdx.z;
  int t = threadIdx.x;
  if (z == 6) {
    int n = blockIdx.y * 96 + blockIdx.x;
    if (n < 768) {
      int i = (n * 256 + t) * 4;
      float4 v = *(const float4*)&hidden[i];
      uint2 o;
      o.x = (unsigned)f2b(v.x) | ((unsigned)f2b(v.y) << 16);
      o.y = (unsigned)f2b(v.z) | ((unsigned)f2b(v.w) << 16);
      *(uint2*)&hb[i] = o;
    } else if (n < 1068) {
      int idx = (n - 768) * 256 + t;
      if (idx < KW_ * H_) {
        int j = idx / H_, d = idx - j * H_;
        float v = (j & 1) ? negk[(j >> 1) * H_ + d] : posk[(j >> 1) * H_ + d];
        kw2s[idx] = v * v * 0.125f * LOG2E;
        kwm[idx] = v * Wmlp[j];
      }
    } else if (n == 1068) {
      __shared__ float red[256];
      red[t] = (t < KW_) ? Wmlp[t] : 0.f;
      __syncthreads();
      for (int s = 128; s > 0; s >>= 1) { if (t < s) red[t] += red[t + s]; __syncthreads(); }
      float sWm = red[0];
      for (int c = t; c < H_; c += 256) c0[c] = sWm * bo[c] + bmlp[0];
    }
    return;
  }
  const float* src; unsigned short* dst; int R, C, r0, c0t;
  if (z < 4) {
    if (blockIdx.x >= 24) return;
    const float* srcs[4] = {Wq, Wk, Wv, Wo};
    src = srcs[z];
    dst = (z < 3) ? qkvT + (size_t)z * 768 * 768 : WoT;
    R = 768; C = 768; c0t = blockIdx.x * 32; r0 = blockIdx.y * 32;
  } else if (z == 4) {
    src = Wdown; dst = WdownT; R = 768; C = 3072;
    c0t = blockIdx.x * 32; r0 = blockIdx.y * 32;
  } else {
    src = Wup; dst = WupT; R = 3072; C = 768;
    c0t = blockIdx.y * 32; r0 = blockIdx.x * 32;
  }
  int tx = t & 31, ty = t >> 5;
#pragma unroll
  for (int i = 0; i < 4; i++)
    tile[ty + i * 8][tx] = src[(size_t)(r0 + ty + i * 8) * C + c0t + tx];
  __syncthreads();
#pragma unroll
  for (int i = 0; i < 4; i++)
    dst[(size_t)(c0t + ty + i * 8) * R + r0 + tx] = f2b(tile[tx][ty + i * 8]);
}

// ---------------- bf16 MFMA GEMM (global_load_lds staging; EPI2=gelu) ----------------
template <int EPI>
__launch_bounds__(256)
__global__ void k_gemm_bt(const unsigned short* __restrict__ A, const unsigned short* __restrict__ BT,
                          int M, int N, int K,
                          float* __restrict__ outF, unsigned short* __restrict__ outB,
                          const float* __restrict__ bias, const float* __restrict__ res) {
  __shared__ __align__(16) unsigned short Asm[128 * 32];
  __shared__ __align__(16) unsigned short Bsm[128 * 32];
  int tid = threadIdx.x;
  int lane = tid & 63, wid = tid >> 6;
  int g = lane >> 4, c16 = lane & 15;
  int wr = wid >> 1, wc = wid & 1;
  int m0 = blockIdx.y * 128, n0 = blockIdx.x * 128;
  f32x4 acc[4][4] = {};
  int ldsrow = lane >> 2, ldscol = (lane & 3) * 8;
  for (int kt = 0; kt < K; kt += 32) {
    __syncthreads();
#pragma unroll
    for (int r = 0; r < 2; r++) {
      int c = wid * 2 + r;
      gload16(A + (size_t)(m0 + c * 16 + ldsrow) * K + kt + ldscol, &Asm[c * 512 + lane * 8]);
      gload16(BT + (size_t)(n0 + c * 16 + ldsrow) * K + kt + ldscol, &Bsm[c * 512 + lane * 8]);
    }
    __syncthreads();
    short8 af[4], bf[4];
#pragma unroll
    for (int mi = 0; mi < 4; mi++) af[mi] = *(const short8*)&Asm[(wr * 64 + mi * 16 + c16) * 32 + g * 8];
#pragma unroll
    for (int ni = 0; ni < 4; ni++) bf[ni] = *(const short8*)&Bsm[(wc * 64 + ni * 16 + c16) * 32 + g * 8];
#pragma unroll
    for (int mi = 0; mi < 4; mi++)
#pragma unroll
      for (int ni = 0; ni < 4; ni++)
        acc[mi][ni] = __builtin_amdgcn_mfma_f32_16x16x32_bf16(af[mi], bf[ni], acc[mi][ni], 0, 0, 0);
  }
#pragma unroll
  for (int mi = 0; mi < 4; mi++)
#pragma unroll
    for (int ni = 0; ni < 4; ni++)
#pragma unroll
      for (int rr = 0; rr < 4; rr++) {
        int row = m0 + wr * 64 + mi * 16 + g * 4 + rr;
        int col = n0 + wc * 64 + ni * 16 + c16;
        float v = acc[mi][ni][rr];
        if (EPI == 0) {
          outB[(size_t)row * N + col] = f2b(v);
        } else if (EPI == 2) {
          float t = v + bias[col];
          float gl = 0.5f * t * (1.f + erff(t * 0.70710678118f));
          outB[(size_t)row * N + col] = f2b(gl);
        }
      }
}

// ---------------- split-K GEMM -> partials (OUTB=1: bf16, else f32) ----------------
template <int OUTB>
__launch_bounds__(256)
__global__ void k_gemm_sk(const unsigned short* __restrict__ A, const unsigned short* __restrict__ BT,
                          int M, int N, int K, int ksl, void* __restrict__ pOut) {
  __shared__ __align__(16) unsigned short Asm[128 * 32];
  __shared__ __align__(16) unsigned short Bsm[128 * 32];
  int tid = threadIdx.x;
  int lane = tid & 63, wid = tid >> 6;
  int g = lane >> 4, c16 = lane & 15;
  int wr = wid >> 1, wc = wid & 1;
  int m0 = blockIdx.y * 128, n0 = blockIdx.x * 128;
  int kstart = blockIdx.z * ksl;
  f32x4 acc[4][4] = {};
  int ldsrow = lane >> 2, ldscol = (lane & 3) * 8;
  for (int kt = 0; kt < ksl; kt += 32) {
    __syncthreads();
#pragma unroll
    for (int r = 0; r < 2; r++) {
      int c = wid * 2 + r;
      gload16(A + (size_t)(m0 + c * 16 + ldsrow) * K + kstart + kt + ldscol, &Asm[c * 512 + lane * 8]);
      gload16(BT + (size_t)(n0 + c * 16 + ldsrow) * K + kstart + kt + ldscol, &Bsm[c * 512 + lane * 8]);
    }
    __syncthreads();
    short8 af[4], bf[4];
#pragma unroll
    for (int mi = 0; mi < 4; mi++) af[mi] = *(const short8*)&Asm[(wr * 64 + mi * 16 + c16) * 32 + g * 8];
#pragma unroll
    for (int ni = 0; ni < 4; ni++) bf[ni] = *(const short8*)&Bsm[(wc * 64 + ni * 16 + c16) * 32 + g * 8];
#pragma unroll
    for (int mi = 0; mi < 4; mi++)
#pragma unroll
      for (int ni = 0; ni < 4; ni++)
        acc[mi][ni] = __builtin_amdgcn_mfma_f32_16x16x32_bf16(af[mi], bf[ni], acc[mi][ni], 0, 0, 0);
  }
#pragma unroll
  for (int mi = 0; mi < 4; mi++)
#pragma unroll
    for (int ni = 0; ni < 4; ni++)
#pragma unroll
      for (int rr = 0; rr < 4; rr++) {
        int row = m0 + wr * 64 + mi * 16 + g * 4 + rr;
        int col = n0 + wc * 64 + ni * 16 + c16;
        if (OUTB) {
          unsigned short* dst = (unsigned short*)pOut + (size_t)blockIdx.z * M * N;
          dst[(size_t)row * N + col] = f2b(acc[mi][ni][rr]);
        } else {
          float* dst = (float*)pOut + (size_t)blockIdx.z * M * N;
          dst[(size_t)row * N + col] = acc[mi][ni][rr];
        }
      }
}

// reduce SPLITS f32 partials (+ optional bias epilogue)
template <int SPLITS, int EPI>
__global__ void k_red(const float* __restrict__ p, const float* __restrict__ bias,
                      float* __restrict__ outF, unsigned short* __restrict__ outB, int N) {
  int i = (blockIdx.x * 256 + threadIdx.x) * 4;
  const size_t MN = (size_t)M_ * N;
  float4 s = *(const float4*)&p[i];
#pragma unroll
  for (int c = 1; c < SPLITS; c++) {
    float4 v = *(const float4*)&p[c * MN + i];
    s.x += v.x; s.y += v.y; s.z += v.z; s.w += v.w;
  }
  if (EPI == 1) {
    int col = i % N;
    s.x += bias[col]; s.y += bias[col + 1]; s.z += bias[col + 2]; s.w += bias[col + 3];
    *(float4*)&outF[i] = s;
  }
  uint2 o;
  o.x = (unsigned)f2b(s.x) | ((unsigned)f2b(s.y) << 16);
  o.y = (unsigned)f2b(s.z) | ((unsigned)f2b(s.w) << 16);
  *(uint2*)&outB[i] = o;
}

// reduce SPLITS bf16 partials -> bf16
template <int SPLITS>
__global__ void k_redb(const unsigned short* __restrict__ p, unsigned short* __restrict__ outB,
                       size_t MN) {
  int i = (blockIdx.x * 256 + threadIdx.x) * 4;
  float s0 = 0.f, s1 = 0.f, s2 = 0.f, s3 = 0.f;
#pragma unroll
  for (int c = 0; c < SPLITS; c++) {
    uint2 v = *(const uint2*)&p[c * MN + i];
    s0 += b2f((unsigned short)(v.x & 0xffffu));
    s1 += b2f((unsigned short)(v.x >> 16));
    s2 += b2f((unsigned short)(v.y & 0xffffu));
    s3 += b2f((unsigned short)(v.y >> 16));
  }
  uint2 o;
  o.x = (unsigned)f2b(s0) | ((unsigned)f2b(s1) << 16);
  o.y = (unsigned)f2b(s2) | ((unsigned)f2b(s3) << 16);
  *(uint2*)&outB[i] = o;
}

// ---------------- fused keyword attention (v10 final — measured best ~87 µs) ----------------
// 1D grid 480 (XCD-clustered: 5 chunk-blocks of one (h,b) share n%8 -> same XCD
// -> L2-served Q/K/V). 512 thr, 1 blk/CU (VGPR bracket: 108 arch + 128 acc ->
// 256-reg slot -> 2 waves/SIMD; structural). Swapped operands
// (S^T = mfma(K'*kw2, Q)); softmax axis q in-lane; NO in-loop barriers; colsum
// inline; 1/colsum folded into vA; packed exp2 outputs ARE the PV B-frag of
// mfma_f32_16x16x16bf16_1k.
__launch_bounds__(512, 2)
__global__ void k_attn(const unsigned short* __restrict__ PQKV,
                       const float* __restrict__ kw2s, const float* __restrict__ kwm,
                       unsigned short* __restrict__ partial) {
  __shared__ __align__(16) char SM[67584];  // QS 18.4KB + VS 18.4KB (prologue) / Ebuf [8][16][132] f32 (epilogue)
  int tid = threadIdx.x;
  int lane = tid & 63, wid = tid >> 6;
  int g = (lane >> 4) & 3, c16 = lane & 15;
  int n = blockIdx.x;
  int chunk = (n >> 3) % NCHUNK;
  int hb = (n & 7) + 8 * (n / (8 * NCHUNK));
  int h = hb >> 3, b = hb & 7;
  const size_t rowbase = (size_t)b * 128 * QKVN;
  const unsigned short* Qbase = PQKV + rowbase + h * HD_;
  const unsigned short* Kbase = Qbase + H_;
  const unsigned short* Vbase = Qbase + 2 * H_;

  unsigned short (*QS)[72] = (unsigned short(*)[72])SM;
  unsigned short (*VS)[72] = (unsigned short(*)[72])(SM + 18432);
  // ---- prologue: stage Q + V rows -> LDS; K own-row frags from global ----
  {
    int kq = tid >> 2, quarter = tid & 3;
    const unsigned short* srcq = Qbase + (size_t)kq * QKVN + quarter * 16;
    ushort8 a0 = *(const ushort8*)srcq;
    ushort8 a1 = *(const ushort8*)(srcq + 8);
    *(ushort8*)&QS[kq][quarter * 16] = a0;
    *(ushort8*)&QS[kq][quarter * 16 + 8] = a1;
    const unsigned short* srcv = Vbase + (size_t)kq * QKVN + quarter * 16;
    ushort8 w0 = *(const ushort8*)srcv;
    ushort8 w1 = *(const ushort8*)(srcv + 8);
    *(ushort8*)&VS[kq][quarter * 16] = w0;
    *(ushort8*)&VS[kq][quarter * 16 + 8] = w1;
  }
  const unsigned short* kpg = Kbase + (size_t)(wid * 16 + c16) * QKVN;
  ushort8 kraw0 = *(const ushort8*)(kpg + g * 8);
  ushort8 kraw1 = *(const ushort8*)(kpg + 32 + g * 8);
  __syncthreads();
  // V raw frags: V[wid*16+4g+j][dt*16+c16]  (VS region unused after this)
  unsigned short vraw[4][4];  // [dt][j]
#pragma unroll
  for (int dt = 0; dt < 4; dt++)
#pragma unroll
    for (int j = 0; j < 4; j++)
      vraw[dt][j] = VS[wid * 16 + 4 * g + j][dt * 16 + c16];

  f32x4 acc[4][8] = {};  // [dt][t] : ctx^T[d=dt*16+4g+rr][q=16t+c16]
  int zo = 0;
  asm volatile("" : "+v"(zo));  // opaque 0: keeps Q ds_reads loop-variant (no LICM)
  for (int ki = 0; ki < KWPER; ki++) {
    int kwi = chunk * KWPER + ki;
    const float* k2p = kw2s + (size_t)kwi * H_ + h * HD_;
    const float* kmp = kwm + (size_t)kwi * H_ + h * HD_;
    // ---- K' = K * kw2 (own 16 rows; A-frag for x32) ----
    short8 kA0, kA1;
    {
      float4 s0 = *(const float4*)(k2p + g * 8);
      float4 s1 = *(const float4*)(k2p + g * 8 + 4);
      float4 s2 = *(const float4*)(k2p + 32 + g * 8);
      float4 s3 = *(const float4*)(k2p + 32 + g * 8 + 4);
      union { unsigned u[4]; short8 v; } p0, p1;
      asm("v_cvt_pk_bf16_f32 %0, %1, %2" : "=v"(p0.u[0]) : "v"(b2f(kraw0[0]) * s0.x), "v"(b2f(kraw0[1]) * s0.y));
      asm("v_cvt_pk_bf16_f32 %0, %1, %2" : "=v"(p0.u[1]) : "v"(b2f(kraw0[2]) * s0.z), "v"(b2f(kraw0[3]) * s0.w));
      asm("v_cvt_pk_bf16_f32 %0, %1, %2" : "=v"(p0.u[2]) : "v"(b2f(kraw0[4]) * s1.x), "v"(b2f(kraw0[5]) * s1.y));
      asm("v_cvt_pk_bf16_f32 %0, %1, %2" : "=v"(p0.u[3]) : "v"(b2f(kraw0[6]) * s1.z), "v"(b2f(kraw0[7]) * s1.w));
      asm("v_cvt_pk_bf16_f32 %0, %1, %2" : "=v"(p1.u[0]) : "v"(b2f(kraw1[0]) * s2.x), "v"(b2f(kraw1[1]) * s2.y));
      asm("v_cvt_pk_bf16_f32 %0, %1, %2" : "=v"(p1.u[1]) : "v"(b2f(kraw1[2]) * s2.z), "v"(b2f(kraw1[3]) * s2.w));
      asm("v_cvt_pk_bf16_f32 %0, %1, %2" : "=v"(p1.u[2]) : "v"(b2f(kraw1[4]) * s3.x), "v"(b2f(kraw1[5]) * s3.y));
      asm("v_cvt_pk_bf16_f32 %0, %1, %2" : "=v"(p1.u[3]) : "v"(b2f(kraw1[6]) * s3.z), "v"(b2f(kraw1[7]) * s3.w));
      kA0 = p0.v; kA1 = p1.v;
    }
    // ---- QK^T swapped + exp2 + inline colsum + direct pack ----
    f32x4 csum = {0.f, 0.f, 0.f, 0.f};
    s4b pw[8];
    __builtin_amdgcn_s_setprio(1);
#pragma unroll
    for (int t = 0; t < 8; t++) {
      short8 q0 = *(const short8*)&QS[16 * t + c16][g * 8 + zo];
      short8 q1 = *(const short8*)&QS[16 * t + c16][32 + g * 8 + zo];
      f32x4 z = {0.f, 0.f, 0.f, 0.f};
      z = __builtin_amdgcn_mfma_f32_16x16x32_bf16(kA0, q0, z, 0, 0, 0);
      z = __builtin_amdgcn_mfma_f32_16x16x32_bf16(kA1, q1, z, 0, 0, 0);
      float e0 = __builtin_amdgcn_exp2f(z[0]);
      float e1 = __builtin_amdgcn_exp2f(z[1]);
      float e2 = __builtin_amdgcn_exp2f(z[2]);
      float e3 = __builtin_amdgcn_exp2f(z[3]);
      csum[0] += e0; csum[1] += e1; csum[2] += e2; csum[3] += e3;
      union { unsigned u[2]; s4b v; } pp;
      asm("v_cvt_pk_bf16_f32 %0, %1, %2" : "=v"(pp.u[0]) : "v"(e0), "v"(e1));
      asm("v_cvt_pk_bf16_f32 %0, %1, %2" : "=v"(pp.u[1]) : "v"(e2), "v"(e3));
      pw[t] = pp.v;
    }
    __builtin_amdgcn_s_setprio(0);
    // ---- butterfly over q (c16) -> per-k reciprocal denominators ----
    float cs[4];
#pragma unroll
    for (int rr = 0; rr < 4; rr++) {
      float s = csum[rr];
      s += __shfl_xor(s, 1);
      s += __shfl_xor(s, 2);
      s += __shfl_xor(s, 4);
      s += __shfl_xor(s, 8);
      cs[rr] = __builtin_amdgcn_rcpf(s);
    }
    // ---- V'' = V * kwm[d] * cs[k-slot] (per-k normalize folded here) ----
    s4b vA[4];
#pragma unroll
    for (int dt = 0; dt < 4; dt++) {
      float km = kmp[dt * 16 + c16];
      union { unsigned u[2]; s4b v; } pv;
      asm("v_cvt_pk_bf16_f32 %0, %1, %2" : "=v"(pv.u[0])
          : "v"(b2f(vraw[dt][0]) * km * cs[0]), "v"(b2f(vraw[dt][1]) * km * cs[1]));
      asm("v_cvt_pk_bf16_f32 %0, %1, %2" : "=v"(pv.u[1])
          : "v"(b2f(vraw[dt][2]) * km * cs[2]), "v"(b2f(vraw[dt][3]) * km * cs[3]));
      vA[dt] = pv.v;
    }
    // ---- PV swapped: acc[dt][t] += V''^T(strip) x E^T ----
    __builtin_amdgcn_s_setprio(1);
#pragma unroll
    for (int dt = 0; dt < 4; dt++)
#pragma unroll
      for (int t = 0; t < 8; t++)
        acc[dt][t] = __builtin_amdgcn_mfma_f32_16x16x16bf16_1k(vA[dt], pw[t], acc[dt][t], 0, 0, 0);
    __builtin_amdgcn_s_setprio(0);
  }
  // ---- epilogue: 8-wave sum via LDS, 4 rounds over dt ----
  float (*Ebuf)[16][132] = (float(*)[16][132])SM;
  int qo = tid & 127, db = (tid >> 7) * 4;
#pragma unroll
  for (int dt = 0; dt < 4; dt++) {
    __syncthreads();
#pragma unroll
    for (int t = 0; t < 8; t++)
#pragma unroll
      for (int rr = 0; rr < 4; rr++)
        Ebuf[wid][4 * g + rr][16 * t + c16] = acc[dt][t][rr];
    __syncthreads();
    float s0 = 0.f, s1 = 0.f, s2 = 0.f, s3 = 0.f;
#pragma unroll
    for (int w = 0; w < 8; w++) {
      s0 += Ebuf[w][db + 0][qo];
      s1 += Ebuf[w][db + 1][qo];
      s2 += Ebuf[w][db + 2][qo];
      s3 += Ebuf[w][db + 3][qo];
    }
    unsigned short* o = partial + (size_t)chunk * M_ * H_ + (size_t)(b * 128 + qo) * H_ + h * HD_ + dt * 16 + db;
    uint2 ov;
    ov.x = (unsigned)f2b(s0) | ((unsigned)f2b(s1) << 16);
    ov.y = (unsigned)f2b(s2) | ((unsigned)f2b(s3) << 16);
    *(uint2*)o = ov;
  }
}

// LayerNorm with fused up-proj split-K (bf16 partials) reduce + bias + residual
__launch_bounds__(256)
__global__ void k_ln2(const unsigned short* __restrict__ pUp, const float* __restrict__ bup,
                      const float* __restrict__ fusedF,
                      const float* __restrict__ gamma, const float* __restrict__ beta,
                      float* __restrict__ out) {
  __shared__ float red[8];
  int row = blockIdx.x, t = threadIdx.x;
  int lane = t & 63, wid = t >> 6;
  const size_t MN = (size_t)M_ * H_;
  const size_t rb = (size_t)row * H_;
  float v[3];
#pragma unroll
  for (int j = 0; j < 3; j++) {
    int c = t + j * 256;
    float x = b2f(pUp[rb + c]) + b2f(pUp[MN + rb + c]) + b2f(pUp[2 * MN + rb + c]) + b2f(pUp[3 * MN + rb + c]);
    v[j] = x + bup[c] + fusedF[rb + c];
  }
  float s = v[0] + v[1] + v[2];
#pragma unroll
  for (int off = 1; off < 64; off <<= 1) s += __shfl_xor(s, off);
  if (lane == 0) red[wid] = s;
  __syncthreads();
  float mu = (red[0] + red[1] + red[2] + red[3]) * (1.f / 768.f);
  float q = 0.f;
#pragma unroll
  for (int j = 0; j < 3; j++) { float d = v[j] - mu; q += d * d; }
#pragma unroll
  for (int off = 1; off < 64; off <<= 1) q += __shfl_xor(q, off);
  if (lane == 0) red[4 + wid] = q;
  __syncthreads();
  float var = (red[4] + red[5] + red[6] + red[7]) * (1.f / 768.f);
  float rstd = rsqrtf(var + 1e-12f);
#pragma unroll
  for (int j = 0; j < 3; j++) {
    int c = t + j * 256;
    out[rb + c] = gamma[c] * ((v[j] - mu) * rstd) + beta[c];
  }
}

// ---------------- launch ----------------

extern "C" void kernel_launch(void* const* d_in, const int* in_sizes, int n_in,
                              void* d_out, int out_size, void* d_ws, size_t ws_size,
                              hipStream_t stream) {
  const float* hidden = (const float*)d_in[0];
  const float* posk   = (const float*)d_in[1];
  const float* negk   = (const float*)d_in[2];
  const float* Wq     = (const float*)d_in[4];
  const float* Wk     = (const float*)d_in[5];
  const float* Wv     = (const float*)d_in[6];
  const float* Wo     = (const float*)d_in[7];
  const float* bo     = (const float*)d_in[8];
  const float* Wmlp   = (const float*)d_in[9];
  const float* bmlp   = (const float*)d_in[10];
  const float* Wdown  = (const float*)d_in[11];
  const float* bdown  = (const float*)d_in[12];
  const float* Wup    = (const float*)d_in[13];
  const float* bup    = (const float*)d_in[14];
  const float* gamma  = (const float*)d_in[15];
  const float* beta   = (const float*)d_in[16];

  char* ws = (char*)d_ws;
  size_t off = 0;
  auto alloc = [&](size_t bytes) -> void* {
    void* p = ws + off;
    off += (bytes + 255) & ~(size_t)255;
    return p;
  };
  unsigned short* hb     = (unsigned short*)alloc((size_t)M_ * H_ * 2);
  unsigned short* qkvT   = (unsigned short*)alloc((size_t)QKVN * H_ * 2);
  unsigned short* WoT    = (unsigned short*)alloc((size_t)H_ * H_ * 2);
  unsigned short* WdownT = (unsigned short*)alloc((size_t)I_ * H_ * 2);
  unsigned short* WupT   = (unsigned short*)alloc((size_t)H_ * I_ * 2);
  unsigned short* PQKV   = (unsigned short*)alloc((size_t)M_ * QKVN * 2);
  float* kw2s    = (float*)alloc((size_t)KW_ * H_ * 4);
  float* kwm     = (float*)alloc((size_t)KW_ * H_ * 4);
  float* c0      = (float*)alloc((size_t)H_ * 4);
  float* partial = (float*)alloc((size_t)10 * M_ * H_ * 4);  // aliased: QKV bf16 sk / attn bf16 x5 / Wo f32 sk / up bf16 sk
  unsigned short* ctxsum = (unsigned short*)alloc((size_t)M_ * H_ * 2);
  float* fusedF  = (float*)alloc((size_t)M_ * H_ * 4);
  unsigned short* fusedB = (unsigned short*)alloc((size_t)M_ * H_ * 2);
  unsigned short* downB  = (unsigned short*)alloc((size_t)M_ * I_ * 2);

  k_prep<<<dim3(96, 24, 7), 256, 0, stream>>>(hidden, Wq, Wk, Wv, Wo, Wdown, Wup,
                                              posk, negk, Wmlp, bmlp, bo,
                                              hb, qkvT, WoT, WdownT, WupT, kw2s, kwm, c0);
  // QKV projection: split-K x2 -> bf16 partials -> bf16 PQKV
  k_gemm_sk<1><<<dim3(18, 8, 2), 256, 0, stream>>>(hb, qkvT, M_, QKVN, H_, 384, partial);
  k_redb<2><<<2304, 256, 0, stream>>>((const unsigned short*)partial, PQKV, (size_t)M_ * QKVN);
  k_attn<<<NCHUNK * NH_ * B_, 512, 0, stream>>>(PQKV, kw2s, kwm, (unsigned short*)partial);
  k_redb<NCHUNK><<<768, 256, 0, stream>>>((const unsigned short*)partial, ctxsum, (size_t)M_ * H_);
  // Wo: split-K x4 (f32 partials) ; reduce adds c0 (= sum(Wmlp)*bo + bmlp)
  k_gemm_sk<0><<<dim3(6, 8, 4), 256, 0, stream>>>(ctxsum, WoT, M_, H_, H_, 192, partial);
  k_red<4, 1><<<768, 256, 0, stream>>>(partial, c0, fusedF, fusedB, H_);
  // down-proj: fused gelu epilogue
  k_gemm_bt<2><<<dim3(24, 8), 256, 0, stream>>>(fusedB, WdownT, M_, I_, H_, nullptr, downB, bdown, nullptr);
  // up-proj: split-K x4 bf16 partials ; reduce + bias + residual + LN fused into k_ln2
  k_gemm_sk<1><<<dim3(6, 8, 4), 256, 0, stream>>>(downB, WupT, M_, H_, I_, 768, partial);
  k_ln2<<<M_, 256, 0, stream>>>((const unsigned short*)partial, bup, fusedF, gamma, beta, (float*)d_out);
}